// Round 4
// baseline (186.210 us; speedup 1.0000x reference)
//
#include <hip/hip_runtime.h>

#define B_ 8
#define C_ 512
#define N_ 2304
#define CQ 64

typedef float f32x4 __attribute__((ext_vector_type(4)));
typedef float f32x16 __attribute__((ext_vector_type(16)));
typedef short bf16x8 __attribute__((ext_vector_type(8)));
typedef unsigned short u16x8 __attribute__((ext_vector_type(8)));
typedef int i32x4 __attribute__((ext_vector_type(4)));

__device__ __forceinline__ unsigned short f2bf(float f){
  union { float f; unsigned int u; } v; v.f = f;
  unsigned int r = (v.u + 0x7fffu + ((v.u >> 16) & 1u)) >> 16;
  return (unsigned short)r;
}

__device__ __forceinline__ void gload_lds16(const void* g, void* l){
  __builtin_amdgcn_global_load_lds(
      (const __attribute__((address_space(1))) unsigned int*)g,
      (__attribute__((address_space(3))) unsigned int*)l, 16, 0, 0);
}

// ---------------- transpose: x [B][C][N] f32 -> xt [B][N][C] bf16 ----------------
__global__ __launch_bounds__(256) void k_transpose(const float* __restrict__ x,
                                                   unsigned short* __restrict__ xt){
  __shared__ float T[64*68];
  int i = blockIdx.x;
  int b = i & 7; int r = i >> 3;
  int ct = r & 7, nt = r >> 3;
  int c0 = ct << 6, n0 = nt << 6;
  int t = threadIdx.x;
  {
    int c = t >> 2, nn = (t & 3) << 4;
    const float* src = x + ((size_t)b*C_ + c0 + c)*N_ + n0 + nn;
    #pragma unroll
    for (int q = 0; q < 4; q++){
      f32x4 v = *(const f32x4*)(src + q*4);
      *(f32x4*)&T[c*68 + nn + q*4] = v;
    }
  }
  __syncthreads();
  {
    int n = t >> 2, cs = (t & 3) << 4;
    u16x8 h0, h1;
    #pragma unroll
    for (int ii = 0; ii < 8; ii++) h0[ii] = f2bf(T[(cs+ii)*68 + n]);
    #pragma unroll
    for (int ii = 0; ii < 8; ii++) h1[ii] = f2bf(T[(cs+8+ii)*68 + n]);
    unsigned short* d = xt + ((size_t)b*N_ + n0 + n)*C_ + c0 + cs;
    *(u16x8*)d = h0;
    *(u16x8*)(d + 8) = h1;
  }
}

// ---------------- projection GEMM ----------------
// MODE 0: Q -> center over o, scale log2e/512, store [B][N][64] bf16
// MODE 1: K -> store [B][N][64] bf16
// MODE 2: V -> store [B][C][N] bf16 with m-perm (bit2<->bit3 within 16-blocks pairing)
template<int MODE>
__global__ __launch_bounds__(256) void k_proj(const unsigned short* __restrict__ xt,
                                              const float* __restrict__ Wm,
                                              const float* __restrict__ bias,
                                              unsigned short* __restrict__ outw){
  __shared__ short Al[64*40];
  __shared__ short Bl[64*40];
  __shared__ float T[64*68];
  int i = blockIdx.x;
  int b = i & 7; int r = i >> 3;
  int nt, o0;
  if (MODE == 2){ nt = r >> 3; o0 = (r & 7) << 6; } else { nt = r; o0 = 0; }
  int n0 = nt << 6;
  int t = threadIdx.x; int w = t >> 6; int l = t & 63;
  int cl = l & 15, g = l >> 4;
  int col = (w << 4) + cl;

  f32x4 acc[4];
  #pragma unroll
  for (int nf = 0; nf < 4; nf++) acc[nf] = (f32x4){0.f,0.f,0.f,0.f};

  for (int kk = 0; kk < 16; kk++){
    int c0k = kk << 5;
    {
      int n = t >> 2, cs8 = (t & 3) << 3;
      u16x8 v = *(const u16x8*)(xt + ((size_t)b*N_ + n0 + n)*C_ + c0k + cs8);
      *(u16x8*)&Al[n*40 + cs8] = v;
    }
    {
      int o = t >> 2, cs8 = (t & 3) << 3;
      const float* s = Wm + (size_t)(o0 + o)*C_ + c0k + cs8;
      f32x4 v0 = *(const f32x4*)s;
      f32x4 v1 = *(const f32x4*)(s + 4);
      u16x8 h;
      #pragma unroll
      for (int j = 0; j < 4; j++) h[j] = f2bf(v0[j]);
      #pragma unroll
      for (int j = 0; j < 4; j++) h[4+j] = f2bf(v1[j]);
      *(u16x8*)&Bl[o*40 + cs8] = h;
    }
    __syncthreads();
    bf16x8 bfr = *(const bf16x8*)&Bl[col*40 + (g << 3)];
    #pragma unroll
    for (int nf = 0; nf < 4; nf++){
      bf16x8 afr = *(const bf16x8*)&Al[((nf << 4) + cl)*40 + (g << 3)];
      acc[nf] = __builtin_amdgcn_mfma_f32_16x16x32_bf16(afr, bfr, acc[nf], 0, 0, 0);
    }
    __syncthreads();
  }

  float bvv = bias[o0 + col];
  #pragma unroll
  for (int nf = 0; nf < 4; nf++)
    #pragma unroll
    for (int rr = 0; rr < 4; rr++)
      T[((nf << 4) + (g << 2) + rr)*68 + col] = acc[nf][rr] + bvv;
  __syncthreads();

  if (MODE == 2){
    int o = t >> 2, j = t & 3;
    u16x8 h0, h1;
    #pragma unroll
    for (int ii = 0; ii < 8; ii++){
      int q2 = (ii & 3) | ((ii & 4) << 1);
      h0[ii] = f2bf(T[(j*16 + q2)*68 + o]);
    }
    #pragma unroll
    for (int ii = 0; ii < 8; ii++){
      int q2 = ((ii & 3) | ((ii & 4) << 1)) + 4;
      h1[ii] = f2bf(T[(j*16 + q2)*68 + o]);
    }
    unsigned short* d = outw + ((size_t)b*C_ + o0 + o)*N_ + n0 + (j << 4);
    *(u16x8*)d = h0;
    *(u16x8*)(d + 8) = h1;
  } else {
    int n = t >> 2, j = t & 3;
    float vals[16]; float s = 0.f;
    #pragma unroll
    for (int ii = 0; ii < 16; ii++){ vals[ii] = T[n*68 + (j << 4) + ii]; s += vals[ii]; }
    s += __shfl_xor(s, 1); s += __shfl_xor(s, 2);
    float mean = (MODE == 0) ? s * (1.f/64.f) : 0.f;
    float scl  = (MODE == 0) ? (1.44269504089f/512.f) : 1.f;
    u16x8 h0, h1;
    #pragma unroll
    for (int ii = 0; ii < 8; ii++) h0[ii] = f2bf((vals[ii]   - mean) * scl);
    #pragma unroll
    for (int ii = 0; ii < 8; ii++) h1[ii] = f2bf((vals[8+ii] - mean) * scl);
    unsigned short* d = outw + ((size_t)b*N_ + n0 + n)*CQ + (j << 4);
    *(u16x8*)d = h0;
    *(u16x8*)(d + 8) = h1;
  }
}

// ---------------- S + exp2 -> P (blocked frag-ready layout) ----------------
// grid: ((nt*4 + ms) << bsh) + b_local; 256 thr, 4 waves (nf = w&1, mh = w>>1).
// Block: n-range 64 (nt), m-range 576 (ms). Pl[bl][mblk=m/16][n][16slots] bf16.
// slot (8a + j) within a 16-m block holds m-offset (j&3)+8*(j>>2)+4a.
__global__ __launch_bounds__(256) void k_sexp(const unsigned short* __restrict__ qw,
                                              const unsigned short* __restrict__ kw,
                                              unsigned short* __restrict__ Pl,
                                              float* __restrict__ lsum_part,
                                              int b0, int bsh){
  int bid = blockIdx.x;
  int bl = bid & ((1 << bsh) - 1);
  int b = b0 + bl;
  int r = bid >> bsh;
  int ms = r & 3; int nt = r >> 2;
  int t = threadIdx.x; int w = t >> 6; int l = t & 63;
  int h = l >> 5, ln = l & 31;
  int nf = w & 1, mh = w >> 1;
  int n = nt*64 + nf*32 + ln;

  const unsigned short* qb = qw + ((size_t)b*N_ + n)*CQ + h*8;
  bf16x8 qf[4];
  #pragma unroll
  for (int kq = 0; kq < 4; kq++) qf[kq] = *(const bf16x8*)(qb + kq*16);

  const unsigned short* kb = kw + ((size_t)b*N_ + ln)*CQ + h*8;
  unsigned short* pb = Pl + ((size_t)bl*144*N_ + n)*16 + h*8;

  float lsum = 0.f;
  for (int mf = 0; mf < 9; mf++){
    int mb32 = ms*18 + mh*9 + mf;           // 32-m block index (0..71)
    const unsigned short* ks = kb + (size_t)mb32*32*CQ;
    f32x16 sv;
    #pragma unroll
    for (int rr = 0; rr < 16; rr++) sv[rr] = 0.f;
    #pragma unroll
    for (int kq = 0; kq < 4; kq++){
      bf16x8 kf = *(const bf16x8*)(ks + kq*16);
      sv = __builtin_amdgcn_mfma_f32_32x32x16_bf16(kf, qf[kq], sv, 0, 0, 0);
    }
    float e[16];
    #pragma unroll
    for (int rr = 0; rr < 16; rr++) e[rr] = exp2f(sv[rr]);
    #pragma unroll
    for (int rr = 0; rr < 16; rr++) lsum += e[rr];
    unsigned int pd[8];
    #pragma unroll
    for (int j = 0; j < 8; j++)
      asm("v_cvt_pk_bf16_f32 %0, %1, %2" : "=v"(pd[j]) : "v"(e[2*j]), "v"(e[2*j+1]));
    i32x4 lo = (i32x4){(int)pd[0],(int)pd[1],(int)pd[2],(int)pd[3]};
    i32x4 hi = (i32x4){(int)pd[4],(int)pd[5],(int)pd[6],(int)pd[7]};
    unsigned short* d = pb + (size_t)(mb32*2)*N_*16;
    *(i32x4*)d = lo;                       // m-block 2*mb32
    *(i32x4*)(d + (size_t)N_*16) = hi;     // m-block 2*mb32+1
  }
  lsum += __shfl_xor(lsum, 32);
  if (l < 32)
    lsum_part[((size_t)bl*8 + ms*2 + mh)*N_ + n] = lsum;
}

// ---------------- PV GEMM + softmax-normalize + residual ----------------
// out[b][c][n] = gamma * (sum_m V[c][m] P[n][m]) / lsum[n] + x[b][c][n]
// tile 64c x 128n, BK=32, 256 thr (4 waves: wc=w&1 c-half, wn=w>>1 n-half).
// A = vw (m-permuted), staged with granule XOR swizzle; B = Pl slabs (dense reads).
__global__ __launch_bounds__(256) void k_pv(const unsigned short* __restrict__ vw,
                                            const unsigned short* __restrict__ Pl,
                                            const float* __restrict__ lsum_part,
                                            const float* __restrict__ x,
                                            const float* __restrict__ gamma_p,
                                            float* __restrict__ out,
                                            int b0, int bsh){
  __shared__ __attribute__((aligned(16))) short At[2][2048];   // [64c][32m] swizzled
  __shared__ __attribute__((aligned(16))) short Bt[2][4096];   // [2mb][128n][16]

  int bid = blockIdx.x;
  int bl = bid & ((1 << bsh) - 1);
  int b = b0 + bl;
  int r = bid >> bsh;
  int cb = r & 7; int nb = r >> 3;          // cb 0..7, nb 0..17
  int c0 = cb*64, n0g = nb*128;
  int t = threadIdx.x; int w = t >> 6; int l = t & 63;
  int h = l >> 5, ln = l & 31;
  int wc = w & 1, wn = w >> 1;

  // --- staging sources (per-lane), linear LDS dest ---
  // A: load i=w covers dest granules w*64+l
  const unsigned short* asrc;
  {
    int Gp = w*64 + l;
    int G = Gp ^ ((Gp >> 2) & 3);
    asrc = vw + ((size_t)b*C_ + c0 + (G >> 2))*N_ + (G & 3)*8;   // + m0
  }
  // B: loads j=0,1 cover dest granules (2w+j)*64+l
  const unsigned short* bsrc[2];
  #pragma unroll
  for (int j = 0; j < 2; j++){
    int g = (2*w + j)*64 + l;
    int mb = g >> 8, rem = g & 255;
    bsrc[j] = Pl + (((size_t)bl*144 + mb)*N_ + n0g + (rem >> 1))*16 + (rem & 1)*8;  // + mblk0*N_*16
  }
  // --- frag read byte offsets ---
  int aro[2];
  {
    int cl2 = wc*32 + ln;
    #pragma unroll
    for (int mb = 0; mb < 2; mb++){
      int Gr = cl2*4 + mb*2 + h;
      aro[mb] = (Gr ^ (cl2 & 3)) * 16;
    }
  }
  int bro[2][2];
  #pragma unroll
  for (int nf = 0; nf < 2; nf++)
    #pragma unroll
    for (int mb = 0; mb < 2; mb++){
      int nl = wn*64 + nf*32 + ln;
      bro[nf][mb] = ((mb*128 + nl)*2 + h)*16;
    }

  f32x16 acc[2];
  #pragma unroll
  for (int nf = 0; nf < 2; nf++)
    #pragma unroll
    for (int rr = 0; rr < 16; rr++) acc[nf][rr] = 0.f;

  // prologue: stage tile 0
  gload_lds16(asrc, &At[0][w*512]);
  gload_lds16(bsrc[0], &Bt[0][(2*w+0)*512]);
  gload_lds16(bsrc[1], &Bt[0][(2*w+1)*512]);
  __syncthreads();

  for (int kt = 0; kt < 72; kt++){
    int p = kt & 1;
    int m1 = (kt == 71) ? 0 : (kt + 1)*32;       // wrap stage harmless
    size_t bstep = (size_t)(m1 >> 4)*N_*16;
    gload_lds16(asrc + m1, &At[p^1][w*512]);
    gload_lds16(bsrc[0] + bstep, &Bt[p^1][(2*w+0)*512]);
    gload_lds16(bsrc[1] + bstep, &Bt[p^1][(2*w+1)*512]);

    const char* Ab = (const char*)At[p];
    const char* Bb = (const char*)Bt[p];
    bf16x8 af[2];
    #pragma unroll
    for (int mb = 0; mb < 2; mb++) af[mb] = *(const bf16x8*)(Ab + aro[mb]);
    #pragma unroll
    for (int nf = 0; nf < 2; nf++){
      #pragma unroll
      for (int mb = 0; mb < 2; mb++){
        bf16x8 bf = *(const bf16x8*)(Bb + bro[nf][mb]);
        acc[nf] = __builtin_amdgcn_mfma_f32_32x32x16_bf16(af[mb], bf, acc[nf], 0, 0, 0);
      }
    }
    __syncthreads();
  }

  // epilogue
  float gmv = gamma_p[0];
  #pragma unroll
  for (int nf = 0; nf < 2; nf++){
    int n = n0g + wn*64 + nf*32 + ln;
    float s = 0.f;
    #pragma unroll
    for (int j = 0; j < 8; j++) s += lsum_part[((size_t)bl*8 + j)*N_ + n];
    float f = gmv / s;
    #pragma unroll
    for (int rr = 0; rr < 16; rr++){
      int c = c0 + wc*32 + (rr & 3) + 8*(rr >> 2) + 4*h;
      size_t idx = ((size_t)b*C_ + c)*N_ + n;
      out[idx] = acc[nf][rr]*f + x[idx];
    }
  }
}

extern "C" void kernel_launch(void* const* d_in, const int* in_sizes, int n_in,
                              void* d_out, int out_size, void* d_ws, size_t ws_size,
                              hipStream_t stream) {
  (void)in_sizes; (void)n_in; (void)out_size;
  const float* x  = (const float*)d_in[0];
  const float* Wq = (const float*)d_in[1];
  const float* bq = (const float*)d_in[2];
  const float* Wk = (const float*)d_in[3];
  const float* bk = (const float*)d_in[4];
  const float* Wv = (const float*)d_in[5];
  const float* bv = (const float*)d_in[6];
  const float* gm = (const float*)d_in[7];
  float* out = (float*)d_out;

  const size_t xt_b   = (size_t)B_*N_*C_*2;        // 18.87 MB
  const size_t qw_b   = (size_t)B_*N_*CQ*2;        // 2.36 MB
  const size_t vw_b   = (size_t)B_*C_*N_*2;        // 18.87 MB

  // pick batch-group size so Pl fits in workspace
  int nbg = 8, bsh = 3;
  for (;;){
    size_t pl_b   = (size_t)nbg*144*N_*16*2;
    size_t reg0   = pl_b > xt_b ? pl_b : xt_b;
    size_t lsum_b = (size_t)nbg*8*N_*4;
    size_t need   = reg0 + 2*qw_b + vw_b + lsum_b;
    if (need <= ws_size || nbg == 1) break;
    nbg >>= 1; bsh--;
  }
  size_t pl_b = (size_t)nbg*144*N_*16*2;
  size_t reg0 = pl_b > xt_b ? pl_b : xt_b;

  char* wsc = (char*)d_ws;
  unsigned short* Pl = (unsigned short*)wsc;            // region0 (aliases xt)
  unsigned short* xt = (unsigned short*)wsc;            // dead before k_sexp
  unsigned short* qw = (unsigned short*)(wsc + reg0);
  unsigned short* kw = (unsigned short*)(wsc + reg0 + qw_b);
  unsigned short* vw = (unsigned short*)(wsc + reg0 + 2*qw_b);
  float* lsum_part   = (float*)(wsc + reg0 + 2*qw_b + vw_b);

  k_transpose<<<2304, 256, 0, stream>>>(x, xt);
  k_proj<0><<<288, 256, 0, stream>>>(xt, Wq, bq, qw);
  k_proj<1><<<288, 256, 0, stream>>>(xt, Wk, bk, kw);
  k_proj<2><<<2304, 256, 0, stream>>>(xt, Wv, bv, vw);

  for (int b0 = 0; b0 < B_; b0 += nbg){
    k_sexp<<<144*nbg, 256, 0, stream>>>(qw, kw, Pl, lsum_part, b0, bsh);
    k_pv<<<144*nbg, 256, 0, stream>>>(vw, Pl, lsum_part, x, gm, out, b0, bsh);
  }
}

// Round 5
// 171.487 us; speedup vs baseline: 1.0859x; 1.0859x over previous
//
#include <hip/hip_runtime.h>

#define B_ 8
#define C_ 512
#define N_ 2304
#define CQ 64

typedef float f32x4 __attribute__((ext_vector_type(4)));
typedef float f32x16 __attribute__((ext_vector_type(16)));
typedef short bf16x8 __attribute__((ext_vector_type(8)));
typedef unsigned short u16x8 __attribute__((ext_vector_type(8)));
typedef int i32x4 __attribute__((ext_vector_type(4)));

__device__ __forceinline__ unsigned short f2bf(float f){
  union { float f; unsigned int u; } v; v.f = f;
  unsigned int r = (v.u + 0x7fffu + ((v.u >> 16) & 1u)) >> 16;
  return (unsigned short)r;
}

__device__ __forceinline__ void gload_lds16(const void* g, void* l){
  __builtin_amdgcn_global_load_lds(
      (const __attribute__((address_space(1))) unsigned int*)g,
      (__attribute__((address_space(3))) unsigned int*)l, 16, 0, 0);
}

// ---------------- transpose: x [B][C][N] f32 -> xt [B][N][C] bf16 ----------------
__global__ __launch_bounds__(256) void k_transpose(const float* __restrict__ x,
                                                   unsigned short* __restrict__ xt){
  __shared__ float T[64*68];
  int i = blockIdx.x;
  int b = i & 7; int r = i >> 3;
  int ct = r & 7, nt = r >> 3;
  int c0 = ct << 6, n0 = nt << 6;
  int t = threadIdx.x;
  {
    int c = t >> 2, nn = (t & 3) << 4;
    const float* src = x + ((size_t)b*C_ + c0 + c)*N_ + n0 + nn;
    #pragma unroll
    for (int q = 0; q < 4; q++){
      f32x4 v = *(const f32x4*)(src + q*4);
      *(f32x4*)&T[c*68 + nn + q*4] = v;
    }
  }
  __syncthreads();
  {
    int n = t >> 2, cs = (t & 3) << 4;
    u16x8 h0, h1;
    #pragma unroll
    for (int ii = 0; ii < 8; ii++) h0[ii] = f2bf(T[(cs+ii)*68 + n]);
    #pragma unroll
    for (int ii = 0; ii < 8; ii++) h1[ii] = f2bf(T[(cs+8+ii)*68 + n]);
    unsigned short* d = xt + ((size_t)b*N_ + n0 + n)*C_ + c0 + cs;
    *(u16x8*)d = h0;
    *(u16x8*)(d + 8) = h1;
  }
}

// ---------------- projection GEMM ----------------
// MODE 0: Q -> center over o, scale log2e/512, store [B][N][64] bf16
// MODE 1: K -> store [B][N][64] bf16
// MODE 2: V -> store [B][C][N] bf16 with m-perm (bit2<->bit3 pairing)
template<int MODE>
__global__ __launch_bounds__(256) void k_proj(const unsigned short* __restrict__ xt,
                                              const float* __restrict__ Wm,
                                              const float* __restrict__ bias,
                                              unsigned short* __restrict__ outw){
  __shared__ short Al[64*40];
  __shared__ short Bl[64*40];
  __shared__ float T[64*68];
  int i = blockIdx.x;
  int b = i & 7; int r = i >> 3;
  int nt, o0;
  if (MODE == 2){ nt = r >> 3; o0 = (r & 7) << 6; } else { nt = r; o0 = 0; }
  int n0 = nt << 6;
  int t = threadIdx.x; int w = t >> 6; int l = t & 63;
  int cl = l & 15, g = l >> 4;
  int col = (w << 4) + cl;

  f32x4 acc[4];
  #pragma unroll
  for (int nf = 0; nf < 4; nf++) acc[nf] = (f32x4){0.f,0.f,0.f,0.f};

  for (int kk = 0; kk < 16; kk++){
    int c0k = kk << 5;
    {
      int n = t >> 2, cs8 = (t & 3) << 3;
      u16x8 v = *(const u16x8*)(xt + ((size_t)b*N_ + n0 + n)*C_ + c0k + cs8);
      *(u16x8*)&Al[n*40 + cs8] = v;
    }
    {
      int o = t >> 2, cs8 = (t & 3) << 3;
      const float* s = Wm + (size_t)(o0 + o)*C_ + c0k + cs8;
      f32x4 v0 = *(const f32x4*)s;
      f32x4 v1 = *(const f32x4*)(s + 4);
      u16x8 h;
      #pragma unroll
      for (int j = 0; j < 4; j++) h[j] = f2bf(v0[j]);
      #pragma unroll
      for (int j = 0; j < 4; j++) h[4+j] = f2bf(v1[j]);
      *(u16x8*)&Bl[o*40 + cs8] = h;
    }
    __syncthreads();
    bf16x8 bfr = *(const bf16x8*)&Bl[col*40 + (g << 3)];
    #pragma unroll
    for (int nf = 0; nf < 4; nf++){
      bf16x8 afr = *(const bf16x8*)&Al[((nf << 4) + cl)*40 + (g << 3)];
      acc[nf] = __builtin_amdgcn_mfma_f32_16x16x32_bf16(afr, bfr, acc[nf], 0, 0, 0);
    }
    __syncthreads();
  }

  float bvv = bias[o0 + col];
  #pragma unroll
  for (int nf = 0; nf < 4; nf++)
    #pragma unroll
    for (int rr = 0; rr < 4; rr++)
      T[((nf << 4) + (g << 2) + rr)*68 + col] = acc[nf][rr] + bvv;
  __syncthreads();

  if (MODE == 2){
    int o = t >> 2, j = t & 3;
    u16x8 h0, h1;
    #pragma unroll
    for (int ii = 0; ii < 8; ii++){
      int q2 = (ii & 3) | ((ii & 4) << 1);
      h0[ii] = f2bf(T[(j*16 + q2)*68 + o]);
    }
    #pragma unroll
    for (int ii = 0; ii < 8; ii++){
      int q2 = ((ii & 3) | ((ii & 4) << 1)) + 4;
      h1[ii] = f2bf(T[(j*16 + q2)*68 + o]);
    }
    unsigned short* d = outw + ((size_t)b*C_ + o0 + o)*N_ + n0 + (j << 4);
    *(u16x8*)d = h0;
    *(u16x8*)(d + 8) = h1;
  } else {
    int n = t >> 2, j = t & 3;
    float vals[16]; float s = 0.f;
    #pragma unroll
    for (int ii = 0; ii < 16; ii++){ vals[ii] = T[n*68 + (j << 4) + ii]; s += vals[ii]; }
    s += __shfl_xor(s, 1); s += __shfl_xor(s, 2);
    float mean = (MODE == 0) ? s * (1.f/64.f) : 0.f;
    float scl  = (MODE == 0) ? (1.44269504089f/512.f) : 1.f;
    u16x8 h0, h1;
    #pragma unroll
    for (int ii = 0; ii < 8; ii++) h0[ii] = f2bf((vals[ii]   - mean) * scl);
    #pragma unroll
    for (int ii = 0; ii < 8; ii++) h1[ii] = f2bf((vals[8+ii] - mean) * scl);
    unsigned short* d = outw + ((size_t)b*N_ + n0 + n)*CQ + (j << 4);
    *(u16x8*)d = h0;
    *(u16x8*)(d + 8) = h1;
  }
}

// ---------------- S + exp2 -> P (blocked frag-ready layout) ----------------
__global__ __launch_bounds__(256) void k_sexp(const unsigned short* __restrict__ qw,
                                              const unsigned short* __restrict__ kw,
                                              unsigned short* __restrict__ Pl,
                                              float* __restrict__ lsum_part,
                                              int b0, int bsh){
  int bid = blockIdx.x;
  int bl = bid & ((1 << bsh) - 1);
  int b = b0 + bl;
  int r = bid >> bsh;
  int ms = r & 3; int nt = r >> 2;
  int t = threadIdx.x; int w = t >> 6; int l = t & 63;
  int h = l >> 5, ln = l & 31;
  int nf = w & 1, mh = w >> 1;
  int n = nt*64 + nf*32 + ln;

  const unsigned short* qb = qw + ((size_t)b*N_ + n)*CQ + h*8;
  bf16x8 qf[4];
  #pragma unroll
  for (int kq = 0; kq < 4; kq++) qf[kq] = *(const bf16x8*)(qb + kq*16);

  const unsigned short* kb = kw + ((size_t)b*N_ + ln)*CQ + h*8;
  unsigned short* pb = Pl + ((size_t)bl*144*N_ + n)*16 + h*8;

  float lsum = 0.f;
  for (int mf = 0; mf < 9; mf++){
    int mb32 = ms*18 + mh*9 + mf;
    const unsigned short* ks = kb + (size_t)mb32*32*CQ;
    f32x16 sv;
    #pragma unroll
    for (int rr = 0; rr < 16; rr++) sv[rr] = 0.f;
    #pragma unroll
    for (int kq = 0; kq < 4; kq++){
      bf16x8 kf = *(const bf16x8*)(ks + kq*16);
      sv = __builtin_amdgcn_mfma_f32_32x32x16_bf16(kf, qf[kq], sv, 0, 0, 0);
    }
    float e[16];
    #pragma unroll
    for (int rr = 0; rr < 16; rr++) e[rr] = exp2f(sv[rr]);
    #pragma unroll
    for (int rr = 0; rr < 16; rr++) lsum += e[rr];
    unsigned int pd[8];
    #pragma unroll
    for (int j = 0; j < 8; j++)
      asm("v_cvt_pk_bf16_f32 %0, %1, %2" : "=v"(pd[j]) : "v"(e[2*j]), "v"(e[2*j+1]));
    i32x4 lo = (i32x4){(int)pd[0],(int)pd[1],(int)pd[2],(int)pd[3]};
    i32x4 hi = (i32x4){(int)pd[4],(int)pd[5],(int)pd[6],(int)pd[7]};
    unsigned short* d = pb + (size_t)(mb32*2)*N_*16;
    *(i32x4*)d = lo;
    *(i32x4*)(d + (size_t)N_*16) = hi;
  }
  lsum += __shfl_xor(lsum, 32);
  if (l < 32)
    lsum_part[((size_t)bl*8 + ms*2 + mh)*N_ + n] = lsum;
}

// ---------------- PV GEMM + softmax-normalize + residual (pipelined) ----------------
// out[b][c][n] = gamma * (sum_m V[c][m] P[n][m]) / lsum[n] + x[b][c][n]
// tile 64c x 128n, BK=32, 4 waves (wc=w&1: c-half, wn=w>>1: n-half).
// A (V) in LDS triple-buffer, staged 2 ahead via global_load_lds, rotate-swizzled.
// B (P) direct global->reg, double-buffered. Raw s_barrier + counted vmcnt(5).
__global__ __launch_bounds__(256) void k_pv(const unsigned short* __restrict__ vw,
                                            const unsigned short* __restrict__ Pl,
                                            const float* __restrict__ lsum_part,
                                            const float* __restrict__ x,
                                            const float* __restrict__ gamma_p,
                                            float* __restrict__ out,
                                            int b0, int bsh){
  __shared__ __attribute__((aligned(16))) short At[3][2048];   // [64c][32m], rotate-swz

  int bid = blockIdx.x;
  int bl = bid & ((1 << bsh) - 1);
  int b = b0 + bl;
  int r = bid >> bsh;
  int cb = r & 7; int nb = r >> 3;
  int c0 = cb*64, n0g = nb*128;
  int t = threadIdx.x; int w = t >> 6; int l = t & 63;
  int h = l >> 5, ln = l & 31;
  int wc = w & 1, wn = w >> 1;

  // --- A staging source: thread covers dest granule t (16B) ---
  const unsigned short* asrc;
  {
    int row = t >> 2, pos = t & 3;
    int gc = (pos - (row >> 1)) & 3;
    asrc = vw + ((size_t)b*C_ + c0 + row)*N_ + gc*8;   // + m0
  }
  // --- A frag read byte offsets (conflict-free rotate) ---
  int aro[2];
  {
    int row = wc*32 + ln;
    #pragma unroll
    for (int mb = 0; mb < 2; mb++){
      int pos = ((mb*2 + h) + (row >> 1)) & 3;
      aro[mb] = (row*4 + pos)*16;
    }
  }
  // --- B: uniform base (SGPR) + per-lane offset; 4 loads/step, fully coalesced ---
  const unsigned short* Pb = Pl + (size_t)bl*144*N_*16;   // batch slab
  int boff = (n0g + wn*64 + ln)*16 + h*8;                 // per-lane (shorts)
  size_t bstep = (size_t)N_*16;                           // one m-block (shorts)

  f32x16 acc[2];
  #pragma unroll
  for (int a = 0; a < 2; a++)
    #pragma unroll
    for (int rr = 0; rr < 16; rr++) acc[a][rr] = 0.f;

  bf16x8 B0[4], B1[4];

  // ---- prologue: stage A(0), load B(0), stage A(1) ----
  gload_lds16(asrc, &At[0][t*8]);
  {
    const unsigned short* p0 = Pb + boff;                 // mblk 0
    const unsigned short* p1 = Pb + bstep + boff;         // mblk 1
    B0[0] = *(const bf16x8*)p0;
    B0[1] = *(const bf16x8*)p1;
    B0[2] = *(const bf16x8*)(p0 + 512);
    B0[3] = *(const bf16x8*)(p1 + 512);
  }
  gload_lds16(asrc + 32, &At[1][t*8]);
  asm volatile("s_waitcnt vmcnt(5)" ::: "memory");        // A(0) landed
  __builtin_amdgcn_s_barrier();
  __builtin_amdgcn_sched_barrier(0);

  size_t bnext = 2*bstep;   // mblk base for B(kt+1)

  // ---- main loop: 12 x 6 steps (buf indices compile-time) ----
  #define PV_STEP(KT, RD, WR, BC, BN)                                          \
  {                                                                            \
    const char* Ab = (const char*)At[RD];                                      \
    bf16x8 a0 = *(const bf16x8*)(Ab + aro[0]);                                 \
    bf16x8 a1 = *(const bf16x8*)(Ab + aro[1]);                                 \
    int m2 = ((KT) + 2 < 72) ? ((KT) + 2)*32 : 0;                              \
    gload_lds16(asrc + m2, &At[WR][t*8]);                                      \
    {                                                                          \
      const unsigned short* p0 = Pb + bnext + boff;                            \
      const unsigned short* p1 = Pb + bnext + bstep + boff;                    \
      BN[0] = *(const bf16x8*)p0;                                              \
      BN[1] = *(const bf16x8*)p1;                                              \
      BN[2] = *(const bf16x8*)(p0 + 512);                                      \
      BN[3] = *(const bf16x8*)(p1 + 512);                                      \
    }                                                                          \
    bnext += 2*bstep;                                                          \
    acc[0] = __builtin_amdgcn_mfma_f32_32x32x16_bf16(a0, BC[0], acc[0], 0,0,0);\
    acc[0] = __builtin_amdgcn_mfma_f32_32x32x16_bf16(a1, BC[1], acc[0], 0,0,0);\
    acc[1] = __builtin_amdgcn_mfma_f32_32x32x16_bf16(a0, BC[2], acc[1], 0,0,0);\
    acc[1] = __builtin_amdgcn_mfma_f32_32x32x16_bf16(a1, BC[3], acc[1], 0,0,0);\
    asm volatile("s_waitcnt vmcnt(5)" ::: "memory");                           \
    __builtin_amdgcn_s_barrier();                                              \
    __builtin_amdgcn_sched_barrier(0);                                         \
  }

  for (int it = 0; it < 12; it++){
    int kt = it*6;
    PV_STEP(kt+0, 0, 2, B0, B1)
    PV_STEP(kt+1, 1, 0, B1, B0)
    PV_STEP(kt+2, 2, 1, B0, B1)
    PV_STEP(kt+3, 0, 2, B1, B0)
    PV_STEP(kt+4, 1, 0, B0, B1)
    PV_STEP(kt+5, 2, 1, B1, B0)
  }
  #undef PV_STEP

  // ---- epilogue ----
  float gmv = gamma_p[0];
  #pragma unroll
  for (int nf = 0; nf < 2; nf++){
    int n = n0g + wn*64 + nf*32 + ln;
    float s = 0.f;
    #pragma unroll
    for (int j = 0; j < 8; j++) s += lsum_part[((size_t)bl*8 + j)*N_ + n];
    float f = gmv / s;
    #pragma unroll
    for (int rr = 0; rr < 16; rr++){
      int c = c0 + wc*32 + (rr & 3) + 8*(rr >> 2) + 4*h;
      size_t idx = ((size_t)b*C_ + c)*N_ + n;
      out[idx] = acc[nf][rr]*f + x[idx];
    }
  }
}

extern "C" void kernel_launch(void* const* d_in, const int* in_sizes, int n_in,
                              void* d_out, int out_size, void* d_ws, size_t ws_size,
                              hipStream_t stream) {
  (void)in_sizes; (void)n_in; (void)out_size;
  const float* x  = (const float*)d_in[0];
  const float* Wq = (const float*)d_in[1];
  const float* bq = (const float*)d_in[2];
  const float* Wk = (const float*)d_in[3];
  const float* bk = (const float*)d_in[4];
  const float* Wv = (const float*)d_in[5];
  const float* bv = (const float*)d_in[6];
  const float* gm = (const float*)d_in[7];
  float* out = (float*)d_out;

  const size_t xt_b   = (size_t)B_*N_*C_*2;
  const size_t qw_b   = (size_t)B_*N_*CQ*2;
  const size_t vw_b   = (size_t)B_*C_*N_*2;

  int nbg = 8, bsh = 3;
  for (;;){
    size_t pl_b   = (size_t)nbg*144*N_*16*2;
    size_t reg0   = pl_b > xt_b ? pl_b : xt_b;
    size_t lsum_b = (size_t)nbg*8*N_*4;
    size_t need   = reg0 + 2*qw_b + vw_b + lsum_b;
    if (need <= ws_size || nbg == 1) break;
    nbg >>= 1; bsh--;
  }
  size_t pl_b = (size_t)nbg*144*N_*16*2;
  size_t reg0 = pl_b > xt_b ? pl_b : xt_b;

  char* wsc = (char*)d_ws;
  unsigned short* Pl = (unsigned short*)wsc;
  unsigned short* xt = (unsigned short*)wsc;
  unsigned short* qw = (unsigned short*)(wsc + reg0);
  unsigned short* kw = (unsigned short*)(wsc + reg0 + qw_b);
  unsigned short* vw = (unsigned short*)(wsc + reg0 + 2*qw_b);
  float* lsum_part   = (float*)(wsc + reg0 + 2*qw_b + vw_b);

  k_transpose<<<2304, 256, 0, stream>>>(x, xt);
  k_proj<0><<<288, 256, 0, stream>>>(xt, Wq, bq, qw);
  k_proj<1><<<288, 256, 0, stream>>>(xt, Wk, bk, kw);
  k_proj<2><<<2304, 256, 0, stream>>>(xt, Wv, bv, vw);

  for (int b0 = 0; b0 < B_; b0 += nbg){
    k_sexp<<<144*nbg, 256, 0, stream>>>(qw, kw, Pl, lsum_part, b0, bsh);
    k_pv<<<144*nbg, 256, 0, stream>>>(vw, Pl, lsum_part, x, gm, out, b0, bsh);
  }
}

// Round 6
// 156.911 us; speedup vs baseline: 1.1867x; 1.0929x over previous
//
#include <hip/hip_runtime.h>

#define B_ 8
#define C_ 512
#define N_ 2304
#define CQ 64

typedef float f32x4 __attribute__((ext_vector_type(4)));
typedef float f32x16 __attribute__((ext_vector_type(16)));
typedef short bf16x8 __attribute__((ext_vector_type(8)));
typedef unsigned short u16x8 __attribute__((ext_vector_type(8)));
typedef int i32x4 __attribute__((ext_vector_type(4)));

__device__ __forceinline__ unsigned short f2bf(float f){
  union { float f; unsigned int u; } v; v.f = f;
  unsigned int r = (v.u + 0x7fffu + ((v.u >> 16) & 1u)) >> 16;
  return (unsigned short)r;
}

__device__ __forceinline__ void gload_lds16(const void* g, void* l){
  __builtin_amdgcn_global_load_lds(
      (const __attribute__((address_space(1))) unsigned int*)g,
      (__attribute__((address_space(3))) unsigned int*)l, 16, 0, 0);
}

// ---------------- transpose: x [B][C][N] f32 -> xt [B][N][C] bf16 ----------------
__global__ __launch_bounds__(256) void k_transpose(const float* __restrict__ x,
                                                   unsigned short* __restrict__ xt){
  __shared__ float T[64*68];
  int i = blockIdx.x;
  int b = i & 7; int r = i >> 3;
  int ct = r & 7, nt = r >> 3;
  int c0 = ct << 6, n0 = nt << 6;
  int t = threadIdx.x;
  {
    int c = t >> 2, nn = (t & 3) << 4;
    const float* src = x + ((size_t)b*C_ + c0 + c)*N_ + n0 + nn;
    #pragma unroll
    for (int q = 0; q < 4; q++){
      f32x4 v = *(const f32x4*)(src + q*4);
      *(f32x4*)&T[c*68 + nn + q*4] = v;
    }
  }
  __syncthreads();
  {
    int n = t >> 2, cs = (t & 3) << 4;
    u16x8 h0, h1;
    #pragma unroll
    for (int ii = 0; ii < 8; ii++) h0[ii] = f2bf(T[(cs+ii)*68 + n]);
    #pragma unroll
    for (int ii = 0; ii < 8; ii++) h1[ii] = f2bf(T[(cs+8+ii)*68 + n]);
    unsigned short* d = xt + ((size_t)b*N_ + n0 + n)*C_ + c0 + cs;
    *(u16x8*)d = h0;
    *(u16x8*)(d + 8) = h1;
  }
}

// ---------------- projection GEMM ----------------
// MODE 0: Q -> center over o, scale log2e/512, store [B][N][64] bf16
// MODE 1: K -> store [B][N][64] bf16
// MODE 2: V -> store [B][C][N] bf16 with m-perm (bit2<->bit3 pairing)
template<int MODE>
__global__ __launch_bounds__(256) void k_proj(const unsigned short* __restrict__ xt,
                                              const float* __restrict__ Wm,
                                              const float* __restrict__ bias,
                                              unsigned short* __restrict__ outw){
  __shared__ short Al[64*40];
  __shared__ short Bl[64*40];
  __shared__ float T[64*68];
  int i = blockIdx.x;
  int b = i & 7; int r = i >> 3;
  int nt, o0;
  if (MODE == 2){ nt = r >> 3; o0 = (r & 7) << 6; } else { nt = r; o0 = 0; }
  int n0 = nt << 6;
  int t = threadIdx.x; int w = t >> 6; int l = t & 63;
  int cl = l & 15, g = l >> 4;
  int col = (w << 4) + cl;

  f32x4 acc[4];
  #pragma unroll
  for (int nf = 0; nf < 4; nf++) acc[nf] = (f32x4){0.f,0.f,0.f,0.f};

  for (int kk = 0; kk < 16; kk++){
    int c0k = kk << 5;
    {
      int n = t >> 2, cs8 = (t & 3) << 3;
      u16x8 v = *(const u16x8*)(xt + ((size_t)b*N_ + n0 + n)*C_ + c0k + cs8);
      *(u16x8*)&Al[n*40 + cs8] = v;
    }
    {
      int o = t >> 2, cs8 = (t & 3) << 3;
      const float* s = Wm + (size_t)(o0 + o)*C_ + c0k + cs8;
      f32x4 v0 = *(const f32x4*)s;
      f32x4 v1 = *(const f32x4*)(s + 4);
      u16x8 h;
      #pragma unroll
      for (int j = 0; j < 4; j++) h[j] = f2bf(v0[j]);
      #pragma unroll
      for (int j = 0; j < 4; j++) h[4+j] = f2bf(v1[j]);
      *(u16x8*)&Bl[o*40 + cs8] = h;
    }
    __syncthreads();
    bf16x8 bfr = *(const bf16x8*)&Bl[col*40 + (g << 3)];
    #pragma unroll
    for (int nf = 0; nf < 4; nf++){
      bf16x8 afr = *(const bf16x8*)&Al[((nf << 4) + cl)*40 + (g << 3)];
      acc[nf] = __builtin_amdgcn_mfma_f32_16x16x32_bf16(afr, bfr, acc[nf], 0, 0, 0);
    }
    __syncthreads();
  }

  float bvv = bias[o0 + col];
  #pragma unroll
  for (int nf = 0; nf < 4; nf++)
    #pragma unroll
    for (int rr = 0; rr < 4; rr++)
      T[((nf << 4) + (g << 2) + rr)*68 + col] = acc[nf][rr] + bvv;
  __syncthreads();

  if (MODE == 2){
    int o = t >> 2, j = t & 3;
    u16x8 h0, h1;
    #pragma unroll
    for (int ii = 0; ii < 8; ii++){
      int q2 = (ii & 3) | ((ii & 4) << 1);
      h0[ii] = f2bf(T[(j*16 + q2)*68 + o]);
    }
    #pragma unroll
    for (int ii = 0; ii < 8; ii++){
      int q2 = ((ii & 3) | ((ii & 4) << 1)) + 4;
      h1[ii] = f2bf(T[(j*16 + q2)*68 + o]);
    }
    unsigned short* d = outw + ((size_t)b*C_ + o0 + o)*N_ + n0 + (j << 4);
    *(u16x8*)d = h0;
    *(u16x8*)(d + 8) = h1;
  } else {
    int n = t >> 2, j = t & 3;
    float vals[16]; float s = 0.f;
    #pragma unroll
    for (int ii = 0; ii < 16; ii++){ vals[ii] = T[n*68 + (j << 4) + ii]; s += vals[ii]; }
    s += __shfl_xor(s, 1); s += __shfl_xor(s, 2);
    float mean = (MODE == 0) ? s * (1.f/64.f) : 0.f;
    float scl  = (MODE == 0) ? (1.44269504089f/512.f) : 1.f;
    u16x8 h0, h1;
    #pragma unroll
    for (int ii = 0; ii < 8; ii++) h0[ii] = f2bf((vals[ii]   - mean) * scl);
    #pragma unroll
    for (int ii = 0; ii < 8; ii++) h1[ii] = f2bf((vals[8+ii] - mean) * scl);
    unsigned short* d = outw + ((size_t)b*N_ + n0 + n)*CQ + (j << 4);
    *(u16x8*)d = h0;
    *(u16x8*)(d + 8) = h1;
  }
}

// ---------------- S + exp2 -> P (blocked frag-ready layout) ----------------
__global__ __launch_bounds__(256) void k_sexp(const unsigned short* __restrict__ qw,
                                              const unsigned short* __restrict__ kw,
                                              unsigned short* __restrict__ Pl,
                                              float* __restrict__ lsum_part,
                                              int b0, int bsh){
  int bid = blockIdx.x;
  int bl = bid & ((1 << bsh) - 1);
  int b = b0 + bl;
  int r = bid >> bsh;
  int ms = r & 3; int nt = r >> 2;
  int t = threadIdx.x; int w = t >> 6; int l = t & 63;
  int h = l >> 5, ln = l & 31;
  int nf = w & 1, mh = w >> 1;
  int n = nt*64 + nf*32 + ln;

  const unsigned short* qb = qw + ((size_t)b*N_ + n)*CQ + h*8;
  bf16x8 qf[4];
  #pragma unroll
  for (int kq = 0; kq < 4; kq++) qf[kq] = *(const bf16x8*)(qb + kq*16);

  const unsigned short* kb = kw + ((size_t)b*N_ + ln)*CQ + h*8;
  unsigned short* pb = Pl + ((size_t)bl*144*N_ + n)*16 + h*8;

  float lsum = 0.f;
  for (int mf = 0; mf < 9; mf++){
    int mb32 = ms*18 + mh*9 + mf;
    const unsigned short* ks = kb + (size_t)mb32*32*CQ;
    f32x16 sv;
    #pragma unroll
    for (int rr = 0; rr < 16; rr++) sv[rr] = 0.f;
    #pragma unroll
    for (int kq = 0; kq < 4; kq++){
      bf16x8 kf = *(const bf16x8*)(ks + kq*16);
      sv = __builtin_amdgcn_mfma_f32_32x32x16_bf16(kf, qf[kq], sv, 0, 0, 0);
    }
    float e[16];
    #pragma unroll
    for (int rr = 0; rr < 16; rr++) e[rr] = exp2f(sv[rr]);
    #pragma unroll
    for (int rr = 0; rr < 16; rr++) lsum += e[rr];
    unsigned int pd[8];
    #pragma unroll
    for (int j = 0; j < 8; j++)
      asm("v_cvt_pk_bf16_f32 %0, %1, %2" : "=v"(pd[j]) : "v"(e[2*j]), "v"(e[2*j+1]));
    i32x4 lo = (i32x4){(int)pd[0],(int)pd[1],(int)pd[2],(int)pd[3]};
    i32x4 hi = (i32x4){(int)pd[4],(int)pd[5],(int)pd[6],(int)pd[7]};
    unsigned short* d = pb + (size_t)(mb32*2)*N_*16;
    *(i32x4*)d = lo;
    *(i32x4*)(d + (size_t)N_*16) = hi;
  }
  lsum += __shfl_xor(lsum, 32);
  if (l < 32)
    lsum_part[((size_t)bl*8 + ms*2 + mh)*N_ + n] = lsum;
}

// ---------------- PV GEMM v3: 128c x 128n tile, BK=64, deep pipeline ----------------
// out[b][c][n] = gamma * (sum_m V[c][m] P[n][m]) / lsum[n] + x[b][c][n]
// 4 waves (wc=w&1 c-half 64, wn=w>>1 n-half 64). 36 K-steps.
// A (V): LDS 3-buffer [128c][64m] rotate-swizzled, staged 2 ahead (4 gload_lds/thr/step).
// B (P): global->reg double-buffer (8 x 16B/thr/step, coalesced).
// One raw s_barrier/step + s_waitcnt vmcnt(12) lgkmcnt(0) (counted, never drains).
__global__ __launch_bounds__(256) void k_pv(const unsigned short* __restrict__ vw,
                                            const unsigned short* __restrict__ Pl,
                                            const float* __restrict__ lsum_part,
                                            const float* __restrict__ x,
                                            const float* __restrict__ gamma_p,
                                            float* __restrict__ out,
                                            int b0, int bsh){
  __shared__ __attribute__((aligned(16))) short At[3][128*64];   // 3 x 16 KB

  int bid = blockIdx.x;
  int bl = bid & ((1 << bsh) - 1);
  int b = b0 + bl;
  int r = bid >> bsh;
  int cb = r & 3; int nb = r >> 2;          // cb 0..3, nb 0..17
  int c0 = cb*128, n0g = nb*128;
  int t = threadIdx.x; int w = t >> 6; int l = t & 63;
  int h = l >> 5, ln = l & 31;
  int wc = w & 1, wn = w >> 1;

  // --- A staging: thread covers granules G = w*256 + j*64 + l (j=0..3) ---
  // row = w*32 + j*8 + (l>>3); stored slot pos=l&7 holds data chunk ((l&7)-(l>>3))&7
  int gc = ((l & 7) - (l >> 3)) & 7;
  const unsigned short* asrc0 = vw + ((size_t)b*C_ + c0 + w*32 + (l >> 3))*N_ + gc*8;
  // --- A frag read byte offsets: row = wc*64+cf*32+ln, chunk = mb*2+h, slot=(chunk+row)&7
  int aro[2][4];
  #pragma unroll
  for (int cf = 0; cf < 2; cf++)
    #pragma unroll
    for (int mb = 0; mb < 4; mb++){
      int row = wc*64 + cf*32 + ln;
      aro[cf][mb] = (row*8 + ((mb*2 + h + row) & 7)) * 16;
    }
  // --- B: per-lane offsets into Pl slab ---
  const unsigned short* Pb = Pl + (size_t)bl*144*N_*16;
  size_t bstep = (size_t)N_*16;              // one 16-m block (shorts)
  int boff[2];
  #pragma unroll
  for (int nf = 0; nf < 2; nf++)
    boff[nf] = (n0g + wn*64 + nf*32 + ln)*16 + h*8;

  f32x16 acc[2][2];
  #pragma unroll
  for (int cf = 0; cf < 2; cf++)
    #pragma unroll
    for (int nf = 0; nf < 2; nf++)
      #pragma unroll
      for (int rr = 0; rr < 16; rr++) acc[cf][nf][rr] = 0.f;

  bf16x8 Bx[2][4], By[2][4];

  // ---- prologue: stage A(0), A(1); load B(0) ----
  #pragma unroll
  for (int j = 0; j < 4; j++)
    gload_lds16(asrc0 + (size_t)j*8*N_, &At[0][w*2048 + j*512]);
  #pragma unroll
  for (int j = 0; j < 4; j++)
    gload_lds16(asrc0 + (size_t)j*8*N_ + 64, &At[1][w*2048 + j*512]);
  #pragma unroll
  for (int nf = 0; nf < 2; nf++)
    #pragma unroll
    for (int mb = 0; mb < 4; mb++)
      Bx[nf][mb] = *(const bf16x8*)(Pb + (size_t)mb*bstep + boff[nf]);
  asm volatile("s_waitcnt vmcnt(12)" ::: "memory");   // A(0) landed
  __builtin_amdgcn_s_barrier();
  __builtin_amdgcn_sched_barrier(0);

  #define PV_STEP(KT, RD, WR, BC, BN)                                           \
  {                                                                             \
    const char* Ab = (const char*)At[RD];                                       \
    bf16x8 a_[2][4];                                                            \
    _Pragma("unroll")                                                           \
    for (int cf = 0; cf < 2; cf++)                                              \
      _Pragma("unroll")                                                         \
      for (int mb = 0; mb < 4; mb++)                                            \
        a_[cf][mb] = *(const bf16x8*)(Ab + aro[cf][mb]);                        \
    int m2 = ((KT) + 2 < 36) ? ((KT) + 2)*64 : 0;                               \
    _Pragma("unroll")                                                           \
    for (int j = 0; j < 4; j++)                                                 \
      gload_lds16(asrc0 + (size_t)j*8*N_ + m2, &At[WR][w*2048 + j*512]);        \
    {                                                                           \
      size_t mb1 = (size_t)((((KT) + 1 < 36) ? ((KT) + 1)*4 : 0));              \
      _Pragma("unroll")                                                         \
      for (int nf = 0; nf < 2; nf++)                                            \
        _Pragma("unroll")                                                       \
        for (int mb = 0; mb < 4; mb++)                                          \
          BN[nf][mb] = *(const bf16x8*)(Pb + (mb1 + mb)*bstep + boff[nf]);      \
    }                                                                           \
    _Pragma("unroll")                                                           \
    for (int cf = 0; cf < 2; cf++)                                              \
      _Pragma("unroll")                                                         \
      for (int nf = 0; nf < 2; nf++)                                            \
        _Pragma("unroll")                                                       \
        for (int mb = 0; mb < 4; mb++)                                          \
          acc[cf][nf] = __builtin_amdgcn_mfma_f32_32x32x16_bf16(                \
              a_[cf][mb], BC[nf][mb], acc[cf][nf], 0, 0, 0);                    \
    asm volatile("s_waitcnt vmcnt(12) lgkmcnt(0)" ::: "memory");                \
    __builtin_amdgcn_s_barrier();                                               \
    __builtin_amdgcn_sched_barrier(0);                                          \
  }

  for (int it = 0; it < 6; it++){
    int kt = it*6;
    PV_STEP(kt+0, 0, 2, Bx, By)
    PV_STEP(kt+1, 1, 0, By, Bx)
    PV_STEP(kt+2, 2, 1, Bx, By)
    PV_STEP(kt+3, 0, 2, By, Bx)
    PV_STEP(kt+4, 1, 0, Bx, By)
    PV_STEP(kt+5, 2, 1, By, Bx)
  }
  #undef PV_STEP

  // ---- epilogue: out = gamma*(O/lsum) + x ----
  float gmv = gamma_p[0];
  #pragma unroll
  for (int nf = 0; nf < 2; nf++){
    int n = n0g + wn*64 + nf*32 + ln;
    float s = 0.f;
    #pragma unroll
    for (int j = 0; j < 8; j++) s += lsum_part[((size_t)bl*8 + j)*N_ + n];
    float f = gmv / s;
    #pragma unroll
    for (int cf = 0; cf < 2; cf++){
      #pragma unroll
      for (int rr = 0; rr < 16; rr++){
        int c = c0 + wc*64 + cf*32 + (rr & 3) + 8*(rr >> 2) + 4*h;
        size_t idx = ((size_t)b*C_ + c)*N_ + n;
        out[idx] = acc[cf][nf][rr]*f + x[idx];
      }
    }
  }
}

extern "C" void kernel_launch(void* const* d_in, const int* in_sizes, int n_in,
                              void* d_out, int out_size, void* d_ws, size_t ws_size,
                              hipStream_t stream) {
  (void)in_sizes; (void)n_in; (void)out_size;
  const float* x  = (const float*)d_in[0];
  const float* Wq = (const float*)d_in[1];
  const float* bq = (const float*)d_in[2];
  const float* Wk = (const float*)d_in[3];
  const float* bk = (const float*)d_in[4];
  const float* Wv = (const float*)d_in[5];
  const float* bv = (const float*)d_in[6];
  const float* gm = (const float*)d_in[7];
  float* out = (float*)d_out;

  const size_t xt_b   = (size_t)B_*N_*C_*2;
  const size_t qw_b   = (size_t)B_*N_*CQ*2;
  const size_t vw_b   = (size_t)B_*C_*N_*2;

  int nbg = 8, bsh = 3;
  for (;;){
    size_t pl_b   = (size_t)nbg*144*N_*16*2;
    size_t reg0   = pl_b > xt_b ? pl_b : xt_b;
    size_t lsum_b = (size_t)nbg*8*N_*4;
    size_t need   = reg0 + 2*qw_b + vw_b + lsum_b;
    if (need <= ws_size || nbg == 1) break;
    nbg >>= 1; bsh--;
  }
  size_t pl_b = (size_t)nbg*144*N_*16*2;
  size_t reg0 = pl_b > xt_b ? pl_b : xt_b;

  char* wsc = (char*)d_ws;
  unsigned short* Pl = (unsigned short*)wsc;
  unsigned short* xt = (unsigned short*)wsc;
  unsigned short* qw = (unsigned short*)(wsc + reg0);
  unsigned short* kw = (unsigned short*)(wsc + reg0 + qw_b);
  unsigned short* vw = (unsigned short*)(wsc + reg0 + 2*qw_b);
  float* lsum_part   = (float*)(wsc + reg0 + 2*qw_b + vw_b);

  k_transpose<<<2304, 256, 0, stream>>>(x, xt);
  k_proj<0><<<288, 256, 0, stream>>>(xt, Wq, bq, qw);
  k_proj<1><<<288, 256, 0, stream>>>(xt, Wk, bk, kw);
  k_proj<2><<<2304, 256, 0, stream>>>(xt, Wv, bv, vw);

  for (int b0 = 0; b0 < B_; b0 += nbg){
    k_sexp<<<144*nbg, 256, 0, stream>>>(qw, kw, Pl, lsum_part, b0, bsh);
    k_pv<<<72*nbg, 256, 0, stream>>>(vw, Pl, lsum_part, x, gm, out, b0, bsh);
  }
}